// Round 2
// baseline (5576.911 us; speedup 1.0000x reference)
//
#include <hip/hip_runtime.h>
#include <math.h>

#define N_NODES 50000
#define N_EDGES 800000
#define DIM 256

// ---------------- degree / normalization ----------------

__global__ void k_init_deg(float* __restrict__ deg) {
    int i = blockIdx.x * blockDim.x + threadIdx.x;
    if (i < N_NODES) deg[i] = 1.0f;  // self-loop
}

__global__ void k_count_deg(const int* __restrict__ dst, float* __restrict__ deg) {
    int e = blockIdx.x * blockDim.x + threadIdx.x;
    if (e < N_EDGES) atomicAdd(&deg[dst[e]], 1.0f);
}

__global__ void k_dis(float* __restrict__ deg) {
    int i = blockIdx.x * blockDim.x + threadIdx.x;
    if (i < N_NODES) deg[i] = rsqrtf(deg[i]);
}

// ---------------- aggregation: out = A_hat_norm @ in ----------------
// self-loop term: out[i] = dis[i]^2 * in[i]   (also initializes out)
__global__ void k_agg_self(const float* __restrict__ in, const float* __restrict__ dis,
                           float* __restrict__ out) {
    int t = blockIdx.x * blockDim.x + threadIdx.x;   // N_NODES*64 threads
    int node = t >> 6;
    int f = (t & 63) << 2;
    if (node < N_NODES) {
        float d = dis[node];
        float s = d * d;
        float4 v = *(const float4*)(in + (size_t)node * DIM + f);
        float4 o;
        o.x = v.x * s; o.y = v.y * s; o.z = v.z * s; o.w = v.w * s;
        *(float4*)(out + (size_t)node * DIM + f) = o;
    }
}

// edge term: out[dst] += dis[src]*dis[dst] * in[src]
__global__ void k_agg_edges(const float* __restrict__ in, const float* __restrict__ dis,
                            const int* __restrict__ src, const int* __restrict__ dst,
                            float* __restrict__ out) {
    int t = blockIdx.x * blockDim.x + threadIdx.x;   // N_EDGES*64 threads
    int e = t >> 6;
    int f = (t & 63) << 2;
    if (e < N_EDGES) {
        int s = src[e];
        int d = dst[e];
        float nrm = dis[s] * dis[d];
        float4 v = *(const float4*)(in + (size_t)s * DIM + f);
        float* op = out + (size_t)d * DIM + f;
        atomicAdd(op + 0, v.x * nrm);
        atomicAdd(op + 1, v.y * nrm);
        atomicAdd(op + 2, v.z * nrm);
        atomicAdd(op + 3, v.w * nrm);
    }
}

// ---------------- GEMM: C = A @ W + b, optional relu ----------------
// A [N_NODES, 256] row-major, W [256, 256] row-major, C [N_NODES, 256]
#define BM 64
#define BN 64
#define BK 32

__global__ __launch_bounds__(256) void k_gemm(const float* __restrict__ A,
                                              const float* __restrict__ W,
                                              const float* __restrict__ bias,
                                              float* __restrict__ C, int doRelu) {
    __shared__ float As[BM][36];   // padded stride 36
    __shared__ float Ws[BK][BN];

    int tid = threadIdx.x;
    int tx = tid & 15;       // col group 0..15
    int ty = tid >> 4;       // row group 0..15
    int rowBase = blockIdx.y * BM;
    int colBase = blockIdx.x * BN;

    float acc[4][4] = {{0.f}};

    for (int k0 = 0; k0 < DIM; k0 += BK) {
        // load A tile 64x32: thread loads 8 floats (2 x float4)
        {
            int r = tid >> 2;            // 0..63
            int c = (tid & 3) << 3;      // 0,8,16,24
            int grow = rowBase + r;
            float4 v0 = make_float4(0.f, 0.f, 0.f, 0.f);
            float4 v1 = make_float4(0.f, 0.f, 0.f, 0.f);
            if (grow < N_NODES) {
                const float* p = A + (size_t)grow * DIM + k0 + c;
                v0 = *(const float4*)p;
                v1 = *(const float4*)(p + 4);
            }
            *(float4*)&As[r][c]     = v0;
            *(float4*)&As[r][c + 4] = v1;
        }
        // load W tile 32x64
        {
            int r = tid >> 3;            // 0..31
            int c = (tid & 7) << 3;      // 0,8,...,56
            const float* p = W + (size_t)(k0 + r) * DIM + colBase + c;
            *(float4*)&Ws[r][c]     = *(const float4*)p;
            *(float4*)&Ws[r][c + 4] = *(const float4*)(p + 4);
        }
        __syncthreads();

#pragma unroll
        for (int k = 0; k < BK; ++k) {
            float a[4], w[4];
#pragma unroll
            for (int i = 0; i < 4; ++i) a[i] = As[ty * 4 + i][k];
#pragma unroll
            for (int j = 0; j < 4; ++j) w[j] = Ws[k][tx * 4 + j];
#pragma unroll
            for (int i = 0; i < 4; ++i)
#pragma unroll
                for (int j = 0; j < 4; ++j)
                    acc[i][j] += a[i] * w[j];
        }
        __syncthreads();
    }

    // epilogue: bias + relu, float4 stores
    int gcol = colBase + tx * 4;
    float4 bv = *(const float4*)(bias + gcol);
#pragma unroll
    for (int i = 0; i < 4; ++i) {
        int grow = rowBase + ty * 4 + i;
        if (grow < N_NODES) {
            float4 o;
            o.x = acc[i][0] + bv.x;
            o.y = acc[i][1] + bv.y;
            o.z = acc[i][2] + bv.z;
            o.w = acc[i][3] + bv.w;
            if (doRelu) {
                o.x = fmaxf(o.x, 0.f); o.y = fmaxf(o.y, 0.f);
                o.z = fmaxf(o.z, 0.f); o.w = fmaxf(o.w, 0.f);
            }
            *(float4*)(C + (size_t)grow * DIM + gcol) = o;
        }
    }
}

// ---------------- FC (256->2) + log_softmax, one wave per node ----------------
__global__ void k_fc_logsoftmax(const float* __restrict__ H, const float* __restrict__ Wfc,
                                const float* __restrict__ bfc, float* __restrict__ out) {
    int t = blockIdx.x * blockDim.x + threadIdx.x;   // N_NODES*64 threads
    int node = t >> 6;
    int lane = threadIdx.x & 63;
    if (node >= N_NODES) return;

    float4 h = *(const float4*)(H + (size_t)node * DIM + lane * 4);
    float s0 = 0.f, s1 = 0.f;
#pragma unroll
    for (int j = 0; j < 4; ++j) {
        float hv = (j == 0) ? h.x : (j == 1) ? h.y : (j == 2) ? h.z : h.w;
        int k = lane * 4 + j;
        s0 += hv * Wfc[k * 2 + 0];
        s1 += hv * Wfc[k * 2 + 1];
    }
#pragma unroll
    for (int o = 32; o > 0; o >>= 1) {
        s0 += __shfl_xor(s0, o);
        s1 += __shfl_xor(s1, o);
    }
    if (lane == 0) {
        float l0 = s0 + bfc[0];
        float l1 = s1 + bfc[1];
        float m = fmaxf(l0, l1);
        float lse = m + logf(expf(l0 - m) + expf(l1 - m));
        out[(size_t)node * 2 + 0] = l0 - lse;
        out[(size_t)node * 2 + 1] = l1 - lse;
    }
}

// ---------------- launch ----------------
extern "C" void kernel_launch(void* const* d_in, const int* in_sizes, int n_in,
                              void* d_out, int out_size, void* d_ws, size_t ws_size,
                              hipStream_t stream) {
    const float* x      = (const float*)d_in[0];
    const int* ei       = (const int*)d_in[1];   // harness passes integer inputs as int32
    const int* esrc     = ei;
    const int* edst     = ei + N_EDGES;
    const float* W1  = (const float*)d_in[2];
    const float* b1  = (const float*)d_in[3];
    const float* W2  = (const float*)d_in[4];
    const float* b2  = (const float*)d_in[5];
    const float* Wfc = (const float*)d_in[6];
    const float* bfc = (const float*)d_in[7];
    float* out = (float*)d_out;

    float* bufA = (float*)d_ws;                          // N*DIM agg output
    float* bufB = bufA + (size_t)N_NODES * DIM;          // N*DIM gemm output
    float* dis  = bufB + (size_t)N_NODES * DIM;          // N

    // normalization
    k_init_deg<<<(N_NODES + 255) / 256, 256, 0, stream>>>(dis);
    k_count_deg<<<(N_EDGES + 255) / 256, 256, 0, stream>>>(edst, dis);
    k_dis<<<(N_NODES + 255) / 256, 256, 0, stream>>>(dis);

    dim3 gemmGrid(DIM / BN, (N_NODES + BM - 1) / BM);

    // layer 1: a1 = agg(x) -> bufA ; h1 = relu(a1@W1+b1) -> bufB
    k_agg_self<<<(N_NODES * 64) / 256, 256, 0, stream>>>(x, dis, bufA);
    k_agg_edges<<<(N_EDGES * 64) / 256, 256, 0, stream>>>(x, dis, esrc, edst, bufA);
    k_gemm<<<gemmGrid, 256, 0, stream>>>(bufA, W1, b1, bufB, 1);

    // layer 2: a2 = agg(h1) -> bufA ; h2 = relu(a2@W2+b2) -> bufB
    k_agg_self<<<(N_NODES * 64) / 256, 256, 0, stream>>>(bufB, dis, bufA);
    k_agg_edges<<<(N_EDGES * 64) / 256, 256, 0, stream>>>(bufB, dis, esrc, edst, bufA);
    k_gemm<<<gemmGrid, 256, 0, stream>>>(bufA, W2, b2, bufB, 1);

    // fc + log_softmax
    k_fc_logsoftmax<<<(N_NODES * 64) / 256, 256, 0, stream>>>(bufB, Wfc, bfc, out);
}

// Round 3
// 534.635 us; speedup vs baseline: 10.4313x; 10.4313x over previous
//
#include <hip/hip_runtime.h>
#include <math.h>

#define N_NODES 50000
#define N_EDGES 800000
#define DIM 256
#define SCAN_BLOCKS ((N_NODES + 255) / 256)   // 196

// ---------------- CSR build ----------------

__global__ void k_deg_zero(int* __restrict__ ideg) {
    int i = blockIdx.x * blockDim.x + threadIdx.x;
    if (i < N_NODES) ideg[i] = 0;
}

__global__ void k_deg_count(const int* __restrict__ dst, int* __restrict__ ideg) {
    int e = blockIdx.x * blockDim.x + threadIdx.x;
    if (e < N_EDGES) atomicAdd(&ideg[dst[e]], 1);
}

// per-block inclusive scan -> exclusive offsets + block totals
__global__ __launch_bounds__(256) void k_scan_block(const int* __restrict__ ideg,
                                                    int* __restrict__ rowptr,
                                                    int* __restrict__ blocksum) {
    __shared__ int s[256];
    int t = threadIdx.x;
    int i = blockIdx.x * 256 + t;
    int v = (i < N_NODES) ? ideg[i] : 0;
    s[t] = v;
    for (int off = 1; off < 256; off <<= 1) {
        __syncthreads();
        int add = (t >= off) ? s[t - off] : 0;
        __syncthreads();
        s[t] += add;
    }
    __syncthreads();
    if (i < N_NODES) rowptr[i] = s[t] - v;          // exclusive, block-local
    if (t == 255) blocksum[blockIdx.x] = s[255];
}

__global__ __launch_bounds__(256) void k_scan_tops(int* __restrict__ blocksum,
                                                   int* __restrict__ blockoff) {
    __shared__ int s[256];
    int t = threadIdx.x;
    int v = (t < SCAN_BLOCKS) ? blocksum[t] : 0;
    s[t] = v;
    for (int off = 1; off < 256; off <<= 1) {
        __syncthreads();
        int add = (t >= off) ? s[t - off] : 0;
        __syncthreads();
        s[t] += add;
    }
    __syncthreads();
    if (t < SCAN_BLOCKS) blockoff[t] = s[t] - v;    // exclusive
}

__global__ void k_scan_add(int* __restrict__ rowptr, const int* __restrict__ blockoff,
                           int* __restrict__ cursor) {
    int i = blockIdx.x * blockDim.x + threadIdx.x;
    if (i < N_NODES) {
        int r = rowptr[i] + blockoff[i >> 8];
        rowptr[i] = r;
        cursor[i] = r;
    }
    if (i == 0) rowptr[N_NODES] = N_EDGES;
}

__global__ void k_csr_fill(const int* __restrict__ src, const int* __restrict__ dst,
                           int* __restrict__ cursor, int* __restrict__ csr_src) {
    int e = blockIdx.x * blockDim.x + threadIdx.x;
    if (e < N_EDGES) {
        int pos = atomicAdd(&cursor[dst[e]], 1);
        csr_src[pos] = src[e];
    }
}

__global__ void k_dis(const int* __restrict__ ideg, float* __restrict__ dis) {
    int i = blockIdx.x * blockDim.x + threadIdx.x;
    if (i < N_NODES) dis[i] = rsqrtf((float)(ideg[i] + 1));   // +1 self-loop
}

// ---------------- aggregation (gather, no atomics) ----------------
// out[d] = dis[d] * ( dis[d]*in[d] + sum_{s in N(d)} dis[s]*in[s] )
__global__ __launch_bounds__(256) void k_agg_csr(const float* __restrict__ in,
                                                 const float* __restrict__ dis,
                                                 const int* __restrict__ rowptr,
                                                 const int* __restrict__ csr_src,
                                                 float* __restrict__ out) {
    int node = blockIdx.x * 4 + (threadIdx.x >> 6);
    if (node >= N_NODES) return;
    int lane = threadIdx.x & 63;
    int f = lane << 2;

    float dn = dis[node];
    float4 acc = *(const float4*)(in + (size_t)node * DIM + f);
    acc.x *= dn; acc.y *= dn; acc.z *= dn; acc.w *= dn;

    int e = rowptr[node];
    int eEnd = rowptr[node + 1];
    for (; e + 1 < eEnd; e += 2) {
        int s0 = csr_src[e];
        int s1 = csr_src[e + 1];
        float w0 = dis[s0];
        float w1 = dis[s1];
        float4 v0 = *(const float4*)(in + (size_t)s0 * DIM + f);
        float4 v1 = *(const float4*)(in + (size_t)s1 * DIM + f);
        acc.x += w0 * v0.x + w1 * v1.x;
        acc.y += w0 * v0.y + w1 * v1.y;
        acc.z += w0 * v0.z + w1 * v1.z;
        acc.w += w0 * v0.w + w1 * v1.w;
    }
    if (e < eEnd) {
        int s0 = csr_src[e];
        float w0 = dis[s0];
        float4 v0 = *(const float4*)(in + (size_t)s0 * DIM + f);
        acc.x += w0 * v0.x;
        acc.y += w0 * v0.y;
        acc.z += w0 * v0.z;
        acc.w += w0 * v0.w;
    }
    acc.x *= dn; acc.y *= dn; acc.z *= dn; acc.w *= dn;
    *(float4*)(out + (size_t)node * DIM + f) = acc;
}

// ---------------- GEMM: C = A @ W + b, optional relu ----------------
#define BM 64
#define BN 64
#define BK 32

__global__ __launch_bounds__(256) void k_gemm(const float* __restrict__ A,
                                              const float* __restrict__ W,
                                              const float* __restrict__ bias,
                                              float* __restrict__ C, int doRelu) {
    __shared__ float As[BM][36];
    __shared__ float Ws[BK][BN];

    int tid = threadIdx.x;
    int tx = tid & 15;
    int ty = tid >> 4;
    int rowBase = blockIdx.y * BM;
    int colBase = blockIdx.x * BN;

    float acc[4][4] = {{0.f}};

    for (int k0 = 0; k0 < DIM; k0 += BK) {
        {
            int r = tid >> 2;
            int c = (tid & 3) << 3;
            int grow = rowBase + r;
            float4 v0 = make_float4(0.f, 0.f, 0.f, 0.f);
            float4 v1 = make_float4(0.f, 0.f, 0.f, 0.f);
            if (grow < N_NODES) {
                const float* p = A + (size_t)grow * DIM + k0 + c;
                v0 = *(const float4*)p;
                v1 = *(const float4*)(p + 4);
            }
            *(float4*)&As[r][c]     = v0;
            *(float4*)&As[r][c + 4] = v1;
        }
        {
            int r = tid >> 3;
            int c = (tid & 7) << 3;
            const float* p = W + (size_t)(k0 + r) * DIM + colBase + c;
            *(float4*)&Ws[r][c]     = *(const float4*)p;
            *(float4*)&Ws[r][c + 4] = *(const float4*)(p + 4);
        }
        __syncthreads();

#pragma unroll
        for (int k = 0; k < BK; ++k) {
            float a[4], w[4];
#pragma unroll
            for (int i = 0; i < 4; ++i) a[i] = As[ty * 4 + i][k];
#pragma unroll
            for (int j = 0; j < 4; ++j) w[j] = Ws[k][tx * 4 + j];
#pragma unroll
            for (int i = 0; i < 4; ++i)
#pragma unroll
                for (int j = 0; j < 4; ++j)
                    acc[i][j] += a[i] * w[j];
        }
        __syncthreads();
    }

    int gcol = colBase + tx * 4;
    float4 bv = *(const float4*)(bias + gcol);
#pragma unroll
    for (int i = 0; i < 4; ++i) {
        int grow = rowBase + ty * 4 + i;
        if (grow < N_NODES) {
            float4 o;
            o.x = acc[i][0] + bv.x;
            o.y = acc[i][1] + bv.y;
            o.z = acc[i][2] + bv.z;
            o.w = acc[i][3] + bv.w;
            if (doRelu) {
                o.x = fmaxf(o.x, 0.f); o.y = fmaxf(o.y, 0.f);
                o.z = fmaxf(o.z, 0.f); o.w = fmaxf(o.w, 0.f);
            }
            *(float4*)(C + (size_t)grow * DIM + gcol) = o;
        }
    }
}

// ---------------- FC (256->2) + log_softmax ----------------
__global__ void k_fc_logsoftmax(const float* __restrict__ H, const float* __restrict__ Wfc,
                                const float* __restrict__ bfc, float* __restrict__ out) {
    int t = blockIdx.x * blockDim.x + threadIdx.x;
    int node = t >> 6;
    int lane = threadIdx.x & 63;
    if (node >= N_NODES) return;

    float4 h = *(const float4*)(H + (size_t)node * DIM + lane * 4);
    float s0 = 0.f, s1 = 0.f;
#pragma unroll
    for (int j = 0; j < 4; ++j) {
        float hv = (j == 0) ? h.x : (j == 1) ? h.y : (j == 2) ? h.z : h.w;
        int k = lane * 4 + j;
        s0 += hv * Wfc[k * 2 + 0];
        s1 += hv * Wfc[k * 2 + 1];
    }
#pragma unroll
    for (int o = 32; o > 0; o >>= 1) {
        s0 += __shfl_xor(s0, o);
        s1 += __shfl_xor(s1, o);
    }
    if (lane == 0) {
        float l0 = s0 + bfc[0];
        float l1 = s1 + bfc[1];
        float m = fmaxf(l0, l1);
        float lse = m + logf(expf(l0 - m) + expf(l1 - m));
        out[(size_t)node * 2 + 0] = l0 - lse;
        out[(size_t)node * 2 + 1] = l1 - lse;
    }
}

// ---------------- launch ----------------
extern "C" void kernel_launch(void* const* d_in, const int* in_sizes, int n_in,
                              void* d_out, int out_size, void* d_ws, size_t ws_size,
                              hipStream_t stream) {
    const float* x      = (const float*)d_in[0];
    const int* ei       = (const int*)d_in[1];   // int32 from harness
    const int* esrc     = ei;
    const int* edst     = ei + N_EDGES;
    const float* W1  = (const float*)d_in[2];
    const float* b1  = (const float*)d_in[3];
    const float* W2  = (const float*)d_in[4];
    const float* b2  = (const float*)d_in[5];
    const float* Wfc = (const float*)d_in[6];
    const float* bfc = (const float*)d_in[7];
    float* out = (float*)d_out;

    // workspace layout
    float* bufA = (float*)d_ws;                             // N*DIM
    float* bufB = bufA + (size_t)N_NODES * DIM;             // N*DIM
    float* dis  = bufB + (size_t)N_NODES * DIM;             // N
    int* ideg     = (int*)(dis + N_NODES);                  // N
    int* rowptr   = ideg + N_NODES;                         // N+1
    int* cursor   = rowptr + N_NODES + 1;                   // N
    int* blocksum = cursor + N_NODES;                       // 256
    int* blockoff = blocksum + 256;                         // 256
    int* csr_src  = blockoff + 256;                         // E

    // ---- CSR build (once, reused by both layers) ----
    k_deg_zero<<<(N_NODES + 255) / 256, 256, 0, stream>>>(ideg);
    k_deg_count<<<(N_EDGES + 255) / 256, 256, 0, stream>>>(edst, ideg);
    k_scan_block<<<SCAN_BLOCKS, 256, 0, stream>>>(ideg, rowptr, blocksum);
    k_scan_tops<<<1, 256, 0, stream>>>(blocksum, blockoff);
    k_scan_add<<<(N_NODES + 255) / 256, 256, 0, stream>>>(rowptr, blockoff, cursor);
    k_csr_fill<<<(N_EDGES + 255) / 256, 256, 0, stream>>>(esrc, edst, cursor, csr_src);
    k_dis<<<(N_NODES + 255) / 256, 256, 0, stream>>>(ideg, dis);

    dim3 gemmGrid(DIM / BN, (N_NODES + BM - 1) / BM);
    int aggBlocks = (N_NODES + 3) / 4;   // 4 waves (nodes) per 256-thread block

    // layer 1
    k_agg_csr<<<aggBlocks, 256, 0, stream>>>(x, dis, rowptr, csr_src, bufA);
    k_gemm<<<gemmGrid, 256, 0, stream>>>(bufA, W1, b1, bufB, 1);

    // layer 2
    k_agg_csr<<<aggBlocks, 256, 0, stream>>>(bufB, dis, rowptr, csr_src, bufA);
    k_gemm<<<gemmGrid, 256, 0, stream>>>(bufA, W2, b2, bufB, 1);

    // fc + log_softmax
    k_fc_logsoftmax<<<(N_NODES * 64) / 256, 256, 0, stream>>>(bufB, Wfc, bfc, out);
}

// Round 4
// 309.841 us; speedup vs baseline: 17.9993x; 1.7255x over previous
//
#include <hip/hip_runtime.h>
#include <math.h>

#define N_NODES 50000
#define N_EDGES 800000
#define DIM 256
#define SCAN_BLOCKS ((N_NODES + 255) / 256)   // 196

typedef short bf16x8 __attribute__((ext_vector_type(8)));
typedef float f32x4 __attribute__((ext_vector_type(4)));

__device__ __forceinline__ float bf2f(unsigned short u) {
    return __uint_as_float(((unsigned)u) << 16);
}
__device__ __forceinline__ unsigned short f2bf(float f) {
    unsigned u = __float_as_uint(f);
    return (unsigned short)((u + 0x7fffu + ((u >> 16) & 1u)) >> 16);  // RTNE
}

// ---------------- CSR build ----------------

__global__ void k_deg_zero(int* __restrict__ ideg) {
    int i = blockIdx.x * blockDim.x + threadIdx.x;
    if (i < N_NODES) ideg[i] = 0;
}

__global__ void k_deg_count(const int* __restrict__ dst, int* __restrict__ ideg) {
    int e = blockIdx.x * blockDim.x + threadIdx.x;
    if (e < N_EDGES) atomicAdd(&ideg[dst[e]], 1);
}

__global__ __launch_bounds__(256) void k_scan_block(const int* __restrict__ ideg,
                                                    int* __restrict__ rowptr,
                                                    int* __restrict__ blocksum) {
    __shared__ int s[256];
    int t = threadIdx.x;
    int i = blockIdx.x * 256 + t;
    int v = (i < N_NODES) ? ideg[i] : 0;
    s[t] = v;
    for (int off = 1; off < 256; off <<= 1) {
        __syncthreads();
        int add = (t >= off) ? s[t - off] : 0;
        __syncthreads();
        s[t] += add;
    }
    __syncthreads();
    if (i < N_NODES) rowptr[i] = s[t] - v;
    if (t == 255) blocksum[blockIdx.x] = s[255];
}

__global__ __launch_bounds__(256) void k_scan_tops(int* __restrict__ blocksum,
                                                   int* __restrict__ blockoff) {
    __shared__ int s[256];
    int t = threadIdx.x;
    int v = (t < SCAN_BLOCKS) ? blocksum[t] : 0;
    s[t] = v;
    for (int off = 1; off < 256; off <<= 1) {
        __syncthreads();
        int add = (t >= off) ? s[t - off] : 0;
        __syncthreads();
        s[t] += add;
    }
    __syncthreads();
    if (t < SCAN_BLOCKS) blockoff[t] = s[t] - v;
}

__global__ void k_scan_add(int* __restrict__ rowptr, const int* __restrict__ blockoff,
                           int* __restrict__ cursor) {
    int i = blockIdx.x * blockDim.x + threadIdx.x;
    if (i < N_NODES) {
        int r = rowptr[i] + blockoff[i >> 8];
        rowptr[i] = r;
        cursor[i] = r;
    }
    if (i == 0) rowptr[N_NODES] = N_EDGES;
}

__global__ void k_csr_fill(const int* __restrict__ src, const int* __restrict__ dst,
                           int* __restrict__ cursor, int* __restrict__ csr_src) {
    int e = blockIdx.x * blockDim.x + threadIdx.x;
    if (e < N_EDGES) {
        int pos = atomicAdd(&cursor[dst[e]], 1);
        csr_src[pos] = src[e];
    }
}

__global__ void k_dis(const int* __restrict__ ideg, float* __restrict__ dis) {
    int i = blockIdx.x * blockDim.x + threadIdx.x;
    if (i < N_NODES) dis[i] = rsqrtf((float)(ideg[i] + 1));   // +1 self-loop
}

// ---------------- converts ----------------

__global__ void k_cvt_bf16(const float* __restrict__ x, unsigned short* __restrict__ xb) {
    int i = blockIdx.x * blockDim.x + threadIdx.x;   // one float4 per thread
    float4 v = ((const float4*)x)[i];
    ushort4 o = make_ushort4(f2bf(v.x), f2bf(v.y), f2bf(v.z), f2bf(v.w));
    ((ushort4*)xb)[i] = o;
}

// Wt[n][k] = bf16(W[k][n])  (256x256)
__global__ void k_w_transpose(const float* __restrict__ W, unsigned short* __restrict__ Wt) {
    int n = blockIdx.x;
    int k = threadIdx.x;
    Wt[n * 256 + k] = f2bf(W[k * 256 + n]);
}

// ---------------- aggregation (bf16 gather, f32 accum, no atomics) ----------------
__global__ __launch_bounds__(256) void k_agg_bf16(const unsigned short* __restrict__ in,
                                                  const float* __restrict__ dis,
                                                  const int* __restrict__ rowptr,
                                                  const int* __restrict__ csr_src,
                                                  unsigned short* __restrict__ out) {
    int node = blockIdx.x * 4 + (threadIdx.x >> 6);
    if (node >= N_NODES) return;
    int lane = threadIdx.x & 63;
    int f = lane * 4;

    float dn = dis[node];
    ushort4 sv = *(const ushort4*)(in + (size_t)node * DIM + f);
    float a0 = dn * bf2f(sv.x);
    float a1 = dn * bf2f(sv.y);
    float a2 = dn * bf2f(sv.z);
    float a3 = dn * bf2f(sv.w);

    int e = rowptr[node];
    int eEnd = rowptr[node + 1];
    for (; e + 3 < eEnd; e += 4) {
        int s0 = csr_src[e], s1 = csr_src[e + 1], s2 = csr_src[e + 2], s3 = csr_src[e + 3];
        float w0 = dis[s0], w1 = dis[s1], w2 = dis[s2], w3 = dis[s3];
        ushort4 v0 = *(const ushort4*)(in + (size_t)s0 * DIM + f);
        ushort4 v1 = *(const ushort4*)(in + (size_t)s1 * DIM + f);
        ushort4 v2 = *(const ushort4*)(in + (size_t)s2 * DIM + f);
        ushort4 v3 = *(const ushort4*)(in + (size_t)s3 * DIM + f);
        a0 += w0 * bf2f(v0.x) + w1 * bf2f(v1.x) + w2 * bf2f(v2.x) + w3 * bf2f(v3.x);
        a1 += w0 * bf2f(v0.y) + w1 * bf2f(v1.y) + w2 * bf2f(v2.y) + w3 * bf2f(v3.y);
        a2 += w0 * bf2f(v0.z) + w1 * bf2f(v1.z) + w2 * bf2f(v2.z) + w3 * bf2f(v3.z);
        a3 += w0 * bf2f(v0.w) + w1 * bf2f(v1.w) + w2 * bf2f(v2.w) + w3 * bf2f(v3.w);
    }
    for (; e < eEnd; ++e) {
        int s0 = csr_src[e];
        float w0 = dis[s0];
        ushort4 v0 = *(const ushort4*)(in + (size_t)s0 * DIM + f);
        a0 += w0 * bf2f(v0.x);
        a1 += w0 * bf2f(v0.y);
        a2 += w0 * bf2f(v0.z);
        a3 += w0 * bf2f(v0.w);
    }
    a0 *= dn; a1 *= dn; a2 *= dn; a3 *= dn;
    ushort4 o = make_ushort4(f2bf(a0), f2bf(a1), f2bf(a2), f2bf(a3));
    *(ushort4*)(out + (size_t)node * DIM + f) = o;
}

// ---------------- MFMA GEMM: C = relu(A @ W + b) in bf16 ----------------
// A [M,256] bf16 row-major; Wt [256,256] bf16 with Wt[n][k] = W[k][n]; C [M,256] bf16
// Block: 256 thr = 4 waves (2M x 2N), tile 128M x 64N, BK=32.
__global__ __launch_bounds__(256) void k_gemm_mfma(const unsigned short* __restrict__ A,
                                                   const unsigned short* __restrict__ Wt,
                                                   const float* __restrict__ bias,
                                                   unsigned short* __restrict__ C,
                                                   int M, int doRelu) {
    // k-chunked LDS: [kchunk][row][8 bf16] -> fragment reads are 16B contiguous, conflict-free
    __shared__ unsigned short As[4][128][8];   // 8 KB
    __shared__ unsigned short Bs[4][64][8];    // 4 KB

    int tid = threadIdx.x;
    int lane = tid & 63;
    int wave = tid >> 6;
    int wm = wave >> 1;          // 0..1 (64-row halves)
    int wn = wave & 1;           // 0..1 (32-col halves)
    int lr = lane & 15;          // frag row (A) / col (B)
    int lc = lane >> 4;          // k-chunk 0..3

    int rowBase = blockIdx.y * 128;
    int colBase = blockIdx.x * 64;

    f32x4 acc[4][2] = {};

    int r = tid >> 2;            // 0..63
    int c = tid & 3;             // k-chunk for staging

    for (int k0 = 0; k0 < DIM; k0 += 32) {
        // stage A (two 16B chunks per thread) and B (one)
        float4 z = make_float4(0.f, 0.f, 0.f, 0.f);
        int gr0 = rowBase + r;
        int gr1 = rowBase + r + 64;
        float4 va0 = (gr0 < M) ? *(const float4*)(A + (size_t)gr0 * DIM + k0 + c * 8) : z;
        float4 va1 = (gr1 < M) ? *(const float4*)(A + (size_t)gr1 * DIM + k0 + c * 8) : z;
        float4 vb  = *(const float4*)(Wt + (size_t)(colBase + r) * DIM + k0 + c * 8);
        *(float4*)&As[c][r][0]      = va0;
        *(float4*)&As[c][r + 64][0] = va1;
        *(float4*)&Bs[c][r][0]      = vb;
        __syncthreads();

        bf16x8 af[4], bfr[2];
#pragma unroll
        for (int m = 0; m < 4; ++m)
            af[m] = *(const bf16x8*)&As[lc][wm * 64 + m * 16 + lr][0];
#pragma unroll
        for (int n = 0; n < 2; ++n)
            bfr[n] = *(const bf16x8*)&Bs[lc][wn * 32 + n * 16 + lr][0];
#pragma unroll
        for (int m = 0; m < 4; ++m)
#pragma unroll
            for (int n = 0; n < 2; ++n)
                acc[m][n] = __builtin_amdgcn_mfma_f32_16x16x32_bf16(af[m], bfr[n], acc[m][n], 0, 0, 0);
        __syncthreads();
    }

    // epilogue: bias + relu + bf16 store
#pragma unroll
    for (int m = 0; m < 4; ++m) {
#pragma unroll
        for (int n = 0; n < 2; ++n) {
            int col = colBase + wn * 32 + n * 16 + lr;
            float bv = bias[col];
#pragma unroll
            for (int reg = 0; reg < 4; ++reg) {
                int row = rowBase + wm * 64 + m * 16 + lc * 4 + reg;
                if (row < M) {
                    float v = acc[m][n][reg] + bv;
                    if (doRelu) v = fmaxf(v, 0.f);
                    C[(size_t)row * DIM + col] = f2bf(v);
                }
            }
        }
    }
}

// ---------------- FC (256->2) + log_softmax ----------------
__global__ void k_fc_logsoftmax(const unsigned short* __restrict__ H,
                                const float* __restrict__ Wfc,
                                const float* __restrict__ bfc, float* __restrict__ out) {
    int t = blockIdx.x * blockDim.x + threadIdx.x;
    int node = t >> 6;
    int lane = threadIdx.x & 63;
    if (node >= N_NODES) return;

    ushort4 h = *(const ushort4*)(H + (size_t)node * DIM + lane * 4);
    float hv[4] = {bf2f(h.x), bf2f(h.y), bf2f(h.z), bf2f(h.w)};
    float s0 = 0.f, s1 = 0.f;
#pragma unroll
    for (int j = 0; j < 4; ++j) {
        int k = lane * 4 + j;
        s0 += hv[j] * Wfc[k * 2 + 0];
        s1 += hv[j] * Wfc[k * 2 + 1];
    }
#pragma unroll
    for (int o = 32; o > 0; o >>= 1) {
        s0 += __shfl_xor(s0, o);
        s1 += __shfl_xor(s1, o);
    }
    if (lane == 0) {
        float l0 = s0 + bfc[0];
        float l1 = s1 + bfc[1];
        float m = fmaxf(l0, l1);
        float lse = m + logf(expf(l0 - m) + expf(l1 - m));
        out[(size_t)node * 2 + 0] = l0 - lse;
        out[(size_t)node * 2 + 1] = l1 - lse;
    }
}

// ---------------- launch ----------------
extern "C" void kernel_launch(void* const* d_in, const int* in_sizes, int n_in,
                              void* d_out, int out_size, void* d_ws, size_t ws_size,
                              hipStream_t stream) {
    const float* x      = (const float*)d_in[0];
    const int* ei       = (const int*)d_in[1];   // int32 from harness
    const int* esrc     = ei;
    const int* edst     = ei + N_EDGES;
    const float* W1  = (const float*)d_in[2];
    const float* b1  = (const float*)d_in[3];
    const float* W2  = (const float*)d_in[4];
    const float* b2  = (const float*)d_in[5];
    const float* Wfc = (const float*)d_in[6];
    const float* bfc = (const float*)d_in[7];
    float* out = (float*)d_out;

    // workspace layout (16B-aligned regions first)
    const size_t NF = (size_t)N_NODES * DIM;
    unsigned short* P0 = (unsigned short*)d_ws;          // xb, later a2b
    unsigned short* P1 = P0 + NF;                        // a1b, later h2b
    unsigned short* P2 = P1 + NF;                        // h1b
    unsigned short* W1t = P2 + NF;                       // 256*256
    unsigned short* W2t = W1t + 256 * 256;
    float* dis    = (float*)(W2t + 256 * 256);           // N
    int* ideg     = (int*)(dis + N_NODES);               // N
    int* rowptr   = ideg + N_NODES;                      // N+1
    int* cursor   = rowptr + N_NODES + 1;                // N
    int* blocksum = cursor + N_NODES;                    // 256
    int* blockoff = blocksum + 256;                      // 256
    int* csr_src  = blockoff + 256;                      // E

    // ---- CSR build ----
    k_deg_zero<<<(N_NODES + 255) / 256, 256, 0, stream>>>(ideg);
    k_deg_count<<<(N_EDGES + 255) / 256, 256, 0, stream>>>(edst, ideg);
    k_scan_block<<<SCAN_BLOCKS, 256, 0, stream>>>(ideg, rowptr, blocksum);
    k_scan_tops<<<1, 256, 0, stream>>>(blocksum, blockoff);
    k_scan_add<<<(N_NODES + 255) / 256, 256, 0, stream>>>(rowptr, blockoff, cursor);
    k_csr_fill<<<(N_EDGES + 255) / 256, 256, 0, stream>>>(esrc, edst, cursor, csr_src);
    k_dis<<<(N_NODES + 255) / 256, 256, 0, stream>>>(ideg, dis);

    // ---- converts ----
    k_cvt_bf16<<<(int)(NF / 4 / 256), 256, 0, stream>>>(x, P0);
    k_w_transpose<<<256, 256, 0, stream>>>(W1, W1t);
    k_w_transpose<<<256, 256, 0, stream>>>(W2, W2t);

    int aggBlocks = (N_NODES + 3) / 4;
    dim3 gemmGrid(DIM / 64, (N_NODES + 127) / 128);

    // layer 1: a1 = agg(x) ; h1 = relu(a1@W1+b1)
    k_agg_bf16<<<aggBlocks, 256, 0, stream>>>(P0, dis, rowptr, csr_src, P1);
    k_gemm_mfma<<<gemmGrid, 256, 0, stream>>>(P1, W1t, b1, P2, N_NODES, 1);

    // layer 2: a2 = agg(h1) ; h2 = relu(a2@W2+b2)
    k_agg_bf16<<<aggBlocks, 256, 0, stream>>>(P2, dis, rowptr, csr_src, P0);
    k_gemm_mfma<<<gemmGrid, 256, 0, stream>>>(P0, W2t, b2, P1, N_NODES, 1);

    // fc + log_softmax
    k_fc_logsoftmax<<<(N_NODES * 64) / 256, 256, 0, stream>>>(P1, Wfc, bfc, out);
}

// Round 5
// 295.339 us; speedup vs baseline: 18.8831x; 1.0491x over previous
//
#include <hip/hip_runtime.h>
#include <math.h>

#define N_NODES 50000
#define N_EDGES 800000
#define DIM 256
#define SCAN_BLOCKS ((N_NODES + 255) / 256)   // 196
#define NXBLK 12500                           // (N_NODES*DIM/4)/256 blocks for x convert

typedef short bf16x8 __attribute__((ext_vector_type(8)));
typedef float f32x4 __attribute__((ext_vector_type(4)));

__device__ __forceinline__ float bf2f(unsigned short u) {
    return __uint_as_float(((unsigned)u) << 16);
}
__device__ __forceinline__ unsigned short f2bf(float f) {
    unsigned u = __float_as_uint(f);
    return (unsigned short)((u + 0x7fffu + ((u >> 16) & 1u)) >> 16);  // RTNE
}

// ---------------- fused prologue: ideg zero + x->bf16 + W1/W2 transpose ----------------
__global__ __launch_bounds__(256) void k_prep(const float* __restrict__ x,
                                              unsigned short* __restrict__ xb,
                                              const float* __restrict__ W1,
                                              unsigned short* __restrict__ W1t,
                                              const float* __restrict__ W2,
                                              unsigned short* __restrict__ W2t,
                                              int* __restrict__ ideg) {
    int bid = blockIdx.x;
    int tid = threadIdx.x;
    if (bid < NXBLK) {
        int i = bid * 256 + tid;              // one float4 per thread
        float4 v = ((const float4*)x)[i];
        ((ushort4*)xb)[i] = make_ushort4(f2bf(v.x), f2bf(v.y), f2bf(v.z), f2bf(v.w));
    } else if (bid < NXBLK + 256) {
        int n = bid - NXBLK;
        W1t[n * 256 + tid] = f2bf(W1[tid * 256 + n]);
    } else if (bid < NXBLK + 512) {
        int n = bid - NXBLK - 256;
        W2t[n * 256 + tid] = f2bf(W2[tid * 256 + n]);
    } else {
        int i = (bid - NXBLK - 512) * 256 + tid;
        if (i < N_NODES) ideg[i] = 0;
    }
}

// ---------------- CSR build ----------------

__global__ void k_deg_count(const int* __restrict__ dst, int* __restrict__ ideg) {
    int e = blockIdx.x * blockDim.x + threadIdx.x;
    if (e < N_EDGES) atomicAdd(&ideg[dst[e]], 1);
}

__global__ __launch_bounds__(256) void k_scan_block(const int* __restrict__ ideg,
                                                    int* __restrict__ rowptr,
                                                    int* __restrict__ blocksum) {
    __shared__ int s[256];
    int t = threadIdx.x;
    int i = blockIdx.x * 256 + t;
    int v = (i < N_NODES) ? ideg[i] : 0;
    s[t] = v;
    for (int off = 1; off < 256; off <<= 1) {
        __syncthreads();
        int add = (t >= off) ? s[t - off] : 0;
        __syncthreads();
        s[t] += add;
    }
    __syncthreads();
    if (i < N_NODES) rowptr[i] = s[t] - v;
    if (t == 255) blocksum[blockIdx.x] = s[255];
}

__global__ __launch_bounds__(256) void k_scan_tops(int* __restrict__ blocksum,
                                                   int* __restrict__ blockoff) {
    __shared__ int s[256];
    int t = threadIdx.x;
    int v = (t < SCAN_BLOCKS) ? blocksum[t] : 0;
    s[t] = v;
    for (int off = 1; off < 256; off <<= 1) {
        __syncthreads();
        int add = (t >= off) ? s[t - off] : 0;
        __syncthreads();
        s[t] += add;
    }
    __syncthreads();
    if (t < SCAN_BLOCKS) blockoff[t] = s[t] - v;
}

// global exclusive offsets + cursor init + dis = rsqrt(deg+1)
__global__ void k_scan_add(int* __restrict__ rowptr, const int* __restrict__ blockoff,
                           int* __restrict__ cursor, const int* __restrict__ ideg,
                           float* __restrict__ dis) {
    int i = blockIdx.x * blockDim.x + threadIdx.x;
    if (i < N_NODES) {
        int r = rowptr[i] + blockoff[i >> 8];
        rowptr[i] = r;
        cursor[i] = r;
        dis[i] = rsqrtf((float)(ideg[i] + 1));
    }
    if (i == 0) rowptr[N_NODES] = N_EDGES;
}

__global__ void k_csr_fill(const int* __restrict__ src, const int* __restrict__ dst,
                           int* __restrict__ cursor, int* __restrict__ csr_src) {
    int e = blockIdx.x * blockDim.x + threadIdx.x;
    if (e < N_EDGES) {
        int pos = atomicAdd(&cursor[dst[e]], 1);
        csr_src[pos] = src[e];
    }
}

// ---------------- aggregation (bf16 gather, f32 accum, no atomics) ----------------
__global__ __launch_bounds__(256) void k_agg_bf16(const unsigned short* __restrict__ in,
                                                  const float* __restrict__ dis,
                                                  const int* __restrict__ rowptr,
                                                  const int* __restrict__ csr_src,
                                                  unsigned short* __restrict__ out) {
    int node = blockIdx.x * 4 + (threadIdx.x >> 6);
    if (node >= N_NODES) return;
    int lane = threadIdx.x & 63;
    int f = lane * 4;

    float dn = dis[node];
    ushort4 sv = *(const ushort4*)(in + (size_t)node * DIM + f);
    float a0 = dn * bf2f(sv.x);
    float a1 = dn * bf2f(sv.y);
    float a2 = dn * bf2f(sv.z);
    float a3 = dn * bf2f(sv.w);

    int e = rowptr[node];
    int eEnd = rowptr[node + 1];
    for (; e + 7 < eEnd; e += 8) {
        int s[8];
        float w[8];
        ushort4 v[8];
#pragma unroll
        for (int j = 0; j < 8; ++j) s[j] = csr_src[e + j];
#pragma unroll
        for (int j = 0; j < 8; ++j) v[j] = *(const ushort4*)(in + (size_t)s[j] * DIM + f);
#pragma unroll
        for (int j = 0; j < 8; ++j) w[j] = dis[s[j]];
#pragma unroll
        for (int j = 0; j < 8; ++j) {
            a0 += w[j] * bf2f(v[j].x);
            a1 += w[j] * bf2f(v[j].y);
            a2 += w[j] * bf2f(v[j].z);
            a3 += w[j] * bf2f(v[j].w);
        }
    }
    for (; e < eEnd; ++e) {
        int s0 = csr_src[e];
        float w0 = dis[s0];
        ushort4 v0 = *(const ushort4*)(in + (size_t)s0 * DIM + f);
        a0 += w0 * bf2f(v0.x);
        a1 += w0 * bf2f(v0.y);
        a2 += w0 * bf2f(v0.z);
        a3 += w0 * bf2f(v0.w);
    }
    a0 *= dn; a1 *= dn; a2 *= dn; a3 *= dn;
    *(ushort4*)(out + (size_t)node * DIM + f) =
        make_ushort4(f2bf(a0), f2bf(a1), f2bf(a2), f2bf(a3));
}

// ---------------- MFMA GEMM: C = relu(A @ W + b) in bf16 (layer 1) ----------------
__global__ __launch_bounds__(256) void k_gemm_mfma(const unsigned short* __restrict__ A,
                                                   const unsigned short* __restrict__ Wt,
                                                   const float* __restrict__ bias,
                                                   unsigned short* __restrict__ C,
                                                   int M, int doRelu) {
    __shared__ unsigned short As[4][128][8];   // 8 KB
    __shared__ unsigned short Bs[4][64][8];    // 4 KB

    int tid = threadIdx.x;
    int lane = tid & 63;
    int wave = tid >> 6;
    int wm = wave >> 1;
    int wn = wave & 1;
    int lr = lane & 15;
    int lc = lane >> 4;

    int rowBase = blockIdx.y * 128;
    int colBase = blockIdx.x * 64;

    f32x4 acc[4][2] = {};

    int r = tid >> 2;
    int c = tid & 3;

    for (int k0 = 0; k0 < DIM; k0 += 32) {
        float4 z = make_float4(0.f, 0.f, 0.f, 0.f);
        int gr0 = rowBase + r;
        int gr1 = rowBase + r + 64;
        float4 va0 = (gr0 < M) ? *(const float4*)(A + (size_t)gr0 * DIM + k0 + c * 8) : z;
        float4 va1 = (gr1 < M) ? *(const float4*)(A + (size_t)gr1 * DIM + k0 + c * 8) : z;
        float4 vb  = *(const float4*)(Wt + (size_t)(colBase + r) * DIM + k0 + c * 8);
        *(float4*)&As[c][r][0]      = va0;
        *(float4*)&As[c][r + 64][0] = va1;
        *(float4*)&Bs[c][r][0]      = vb;
        __syncthreads();

        bf16x8 af[4], bfr[2];
#pragma unroll
        for (int m = 0; m < 4; ++m)
            af[m] = *(const bf16x8*)&As[lc][wm * 64 + m * 16 + lr][0];
#pragma unroll
        for (int n = 0; n < 2; ++n)
            bfr[n] = *(const bf16x8*)&Bs[lc][wn * 32 + n * 16 + lr][0];
#pragma unroll
        for (int m = 0; m < 4; ++m)
#pragma unroll
            for (int n = 0; n < 2; ++n)
                acc[m][n] = __builtin_amdgcn_mfma_f32_16x16x32_bf16(af[m], bfr[n], acc[m][n], 0, 0, 0);
        __syncthreads();
    }

#pragma unroll
    for (int m = 0; m < 4; ++m) {
#pragma unroll
        for (int n = 0; n < 2; ++n) {
            int col = colBase + wn * 32 + n * 16 + lr;
            float bv = bias[col];
#pragma unroll
            for (int reg = 0; reg < 4; ++reg) {
                int row = rowBase + wm * 64 + m * 16 + lc * 4 + reg;
                if (row < M) {
                    float v = acc[m][n][reg] + bv;
                    if (doRelu) v = fmaxf(v, 0.f);
                    C[(size_t)row * DIM + col] = f2bf(v);
                }
            }
        }
    }
}

// ---------------- fused GEMM2 + FC + log_softmax ----------------
// A [M,256] bf16; Wt [256,256] (Wt[n][k]=W2[k][n]); h2 = relu(A@W2+b2) kept in f32 regs;
// out[row] = log_softmax(h2[row] @ Wfc + bfc). Tile 128 rows x 256 cols, 4 waves (32 rows each).
__global__ __launch_bounds__(256) void k_gemm_fc(const unsigned short* __restrict__ A,
                                                 const unsigned short* __restrict__ Wt,
                                                 const float* __restrict__ bias,
                                                 const float* __restrict__ Wfc,
                                                 const float* __restrict__ bfc,
                                                 float* __restrict__ out, int M) {
    __shared__ unsigned short As[4][128][8];   // 8 KB
    __shared__ unsigned short Bs[4][256][8];   // 16 KB

    int tid = threadIdx.x;
    int lane = tid & 63;
    int wave = tid >> 6;          // wm: 32-row slice
    int lr = lane & 15;
    int lc = lane >> 4;

    int rowBase = blockIdx.x * 128;

    f32x4 acc[2][16] = {};

    int r = tid >> 2;             // 0..63
    int c = tid & 3;              // k-chunk

    for (int k0 = 0; k0 < DIM; k0 += 32) {
        float4 z = make_float4(0.f, 0.f, 0.f, 0.f);
        int gr0 = rowBase + r;
        int gr1 = rowBase + r + 64;
        float4 va0 = (gr0 < M) ? *(const float4*)(A + (size_t)gr0 * DIM + k0 + c * 8) : z;
        float4 va1 = (gr1 < M) ? *(const float4*)(A + (size_t)gr1 * DIM + k0 + c * 8) : z;
        *(float4*)&As[c][r][0]      = va0;
        *(float4*)&As[c][r + 64][0] = va1;
#pragma unroll
        for (int j = 0; j < 4; ++j) {
            int brow = r + 64 * j;
            *(float4*)&Bs[c][brow][0] = *(const float4*)(Wt + (size_t)brow * DIM + k0 + c * 8);
        }
        __syncthreads();

        bf16x8 af[2];
#pragma unroll
        for (int m = 0; m < 2; ++m)
            af[m] = *(const bf16x8*)&As[lc][wave * 32 + m * 16 + lr][0];
#pragma unroll
        for (int n = 0; n < 16; ++n) {
            bf16x8 bfr = *(const bf16x8*)&Bs[lc][n * 16 + lr][0];
            acc[0][n] = __builtin_amdgcn_mfma_f32_16x16x32_bf16(af[0], bfr, acc[0][n], 0, 0, 0);
            acc[1][n] = __builtin_amdgcn_mfma_f32_16x16x32_bf16(af[1], bfr, acc[1][n], 0, 0, 0);
        }
        __syncthreads();
    }

    // hoist bias + Wfc columns for this lane's 16 cols (col = n*16 + lr)
    float bv[16], wf0[16], wf1[16];
#pragma unroll
    for (int n = 0; n < 16; ++n) {
        int col = n * 16 + lr;
        bv[n]  = bias[col];
        wf0[n] = Wfc[col * 2 + 0];
        wf1[n] = Wfc[col * 2 + 1];
    }
    float bb0 = bfc[0], bb1 = bfc[1];

#pragma unroll
    for (int m = 0; m < 2; ++m) {
#pragma unroll
        for (int reg = 0; reg < 4; ++reg) {
            int row = rowBase + wave * 32 + m * 16 + lc * 4 + reg;
            float s0 = 0.f, s1 = 0.f;
#pragma unroll
            for (int n = 0; n < 16; ++n) {
                float v = fmaxf(acc[m][n][reg] + bv[n], 0.f);   // bias + relu (h2 in f32)
                s0 += v * wf0[n];
                s1 += v * wf1[n];
            }
            // reduce over the 16-lane group (same row)
#pragma unroll
            for (int o = 1; o < 16; o <<= 1) {
                s0 += __shfl_xor(s0, o);
                s1 += __shfl_xor(s1, o);
            }
            if (lr == 0 && row < M) {
                float l0 = s0 + bb0;
                float l1 = s1 + bb1;
                float mx = fmaxf(l0, l1);
                float lse = mx + logf(expf(l0 - mx) + expf(l1 - mx));
                out[(size_t)row * 2 + 0] = l0 - lse;
                out[(size_t)row * 2 + 1] = l1 - lse;
            }
        }
    }
}

// ---------------- launch ----------------
extern "C" void kernel_launch(void* const* d_in, const int* in_sizes, int n_in,
                              void* d_out, int out_size, void* d_ws, size_t ws_size,
                              hipStream_t stream) {
    const float* x      = (const float*)d_in[0];
    const int* ei       = (const int*)d_in[1];   // int32 from harness
    const int* esrc     = ei;
    const int* edst     = ei + N_EDGES;
    const float* W1  = (const float*)d_in[2];
    const float* b1  = (const float*)d_in[3];
    const float* W2  = (const float*)d_in[4];
    const float* b2  = (const float*)d_in[5];
    const float* Wfc = (const float*)d_in[6];
    const float* bfc = (const float*)d_in[7];
    float* out = (float*)d_out;

    const size_t NF = (size_t)N_NODES * DIM;
    unsigned short* P0 = (unsigned short*)d_ws;          // xb, later a2b
    unsigned short* P1 = P0 + NF;                        // a1b
    unsigned short* P2 = P1 + NF;                        // h1b
    unsigned short* W1t = P2 + NF;                       // 256*256
    unsigned short* W2t = W1t + 256 * 256;
    float* dis    = (float*)(W2t + 256 * 256);           // N
    int* ideg     = (int*)(dis + N_NODES);               // N
    int* rowptr   = ideg + N_NODES;                      // N+1
    int* cursor   = rowptr + N_NODES + 1;                // N
    int* blocksum = cursor + N_NODES;                    // 256
    int* blockoff = blocksum + 256;                      // 256
    int* csr_src  = blockoff + 256;                      // E

    // prologue (ideg zero + converts), then CSR build
    k_prep<<<NXBLK + 512 + SCAN_BLOCKS, 256, 0, stream>>>(x, P0, W1, W1t, W2, W2t, ideg);
    k_deg_count<<<(N_EDGES + 255) / 256, 256, 0, stream>>>(edst, ideg);
    k_scan_block<<<SCAN_BLOCKS, 256, 0, stream>>>(ideg, rowptr, blocksum);
    k_scan_tops<<<1, 256, 0, stream>>>(blocksum, blockoff);
    k_scan_add<<<(N_NODES + 255) / 256, 256, 0, stream>>>(rowptr, blockoff, cursor, ideg, dis);
    k_csr_fill<<<(N_EDGES + 255) / 256, 256, 0, stream>>>(esrc, edst, cursor, csr_src);

    int aggBlocks = (N_NODES + 3) / 4;
    dim3 gemmGrid(DIM / 64, (N_NODES + 127) / 128);

    // layer 1
    k_agg_bf16<<<aggBlocks, 256, 0, stream>>>(P0, dis, rowptr, csr_src, P1);
    k_gemm_mfma<<<gemmGrid, 256, 0, stream>>>(P1, W1t, b1, P2, N_NODES, 1);

    // layer 2 + FC fused
    k_agg_bf16<<<aggBlocks, 256, 0, stream>>>(P2, dis, rowptr, csr_src, P0);
    k_gemm_fc<<<(N_NODES + 127) / 128, 256, 0, stream>>>(P0, W2t, b2, Wfc, bfc, out, N_NODES);
}

// Round 6
// 290.388 us; speedup vs baseline: 19.2050x; 1.0171x over previous
//
#include <hip/hip_runtime.h>
#include <math.h>

#define N_NODES 50000
#define N_EDGES 800000
#define DIM 256
#define SCAN_BLOCKS ((N_NODES + 255) / 256)   // 196
#define NXBLK 12500                           // (N_NODES*DIM/4)/256 blocks for x convert
#define NDEGBLK ((N_EDGES + 255) / 256)       // 3125

typedef short bf16x8 __attribute__((ext_vector_type(8)));
typedef float f32x4 __attribute__((ext_vector_type(4)));

__device__ __forceinline__ float bf2f(unsigned short u) {
    return __uint_as_float(((unsigned)u) << 16);
}
__device__ __forceinline__ unsigned short f2bf(float f) {
    unsigned u = __float_as_uint(f);
    return (unsigned short)((u + 0x7fffu + ((u >> 16) & 1u)) >> 16);  // RTNE
}

// ---- fused prologue: x->bf16 + W1/W2 transpose + deg_count (ideg pre-zeroed via memset) ----
__global__ __launch_bounds__(256) void k_prep(const float* __restrict__ x,
                                              unsigned short* __restrict__ xb,
                                              const float* __restrict__ W1,
                                              unsigned short* __restrict__ W1t,
                                              const float* __restrict__ W2,
                                              unsigned short* __restrict__ W2t,
                                              const int* __restrict__ dst,
                                              int* __restrict__ ideg) {
    int bid = blockIdx.x;
    int tid = threadIdx.x;
    if (bid < NXBLK) {
        int i = bid * 256 + tid;              // one float4 per thread
        float4 v = ((const float4*)x)[i];
        ((ushort4*)xb)[i] = make_ushort4(f2bf(v.x), f2bf(v.y), f2bf(v.z), f2bf(v.w));
    } else if (bid < NXBLK + 256) {
        int n = bid - NXBLK;
        W1t[n * 256 + tid] = f2bf(W1[tid * 256 + n]);
    } else if (bid < NXBLK + 512) {
        int n = bid - NXBLK - 256;
        W2t[n * 256 + tid] = f2bf(W2[tid * 256 + n]);
    } else {
        int e = (bid - NXBLK - 512) * 256 + tid;
        if (e < N_EDGES) atomicAdd(&ideg[dst[e]], 1);
    }
}

// ---------------- CSR build ----------------

__global__ __launch_bounds__(256) void k_scan_block(const int* __restrict__ ideg,
                                                    int* __restrict__ rowptr,
                                                    int* __restrict__ blocksum) {
    __shared__ int s[256];
    int t = threadIdx.x;
    int i = blockIdx.x * 256 + t;
    int v = (i < N_NODES) ? ideg[i] : 0;
    s[t] = v;
    for (int off = 1; off < 256; off <<= 1) {
        __syncthreads();
        int add = (t >= off) ? s[t - off] : 0;
        __syncthreads();
        s[t] += add;
    }
    __syncthreads();
    if (i < N_NODES) rowptr[i] = s[t] - v;
    if (t == 255) blocksum[blockIdx.x] = s[255];
}

// tops-scan (redundant per block, LDS) + global offsets + cursor + dis
__global__ __launch_bounds__(256) void k_scan_add(int* __restrict__ rowptr,
                                                  const int* __restrict__ blocksum,
                                                  int* __restrict__ cursor,
                                                  const int* __restrict__ ideg,
                                                  float* __restrict__ dis) {
    __shared__ int s[256];
    int t = threadIdx.x;
    int v = (t < SCAN_BLOCKS) ? blocksum[t] : 0;
    s[t] = v;
    for (int off = 1; off < 256; off <<= 1) {
        __syncthreads();
        int add = (t >= off) ? s[t - off] : 0;
        __syncthreads();
        s[t] += add;
    }
    __syncthreads();
    int excl = s[t] - v;
    __syncthreads();
    s[t] = excl;
    __syncthreads();
    int off = s[blockIdx.x];

    int i = blockIdx.x * 256 + t;
    if (i < N_NODES) {
        int r = rowptr[i] + off;
        rowptr[i] = r;
        cursor[i] = r;
        dis[i] = rsqrtf((float)(ideg[i] + 1));
    }
    if (i == 0) rowptr[N_NODES] = N_EDGES;
}

__global__ void k_csr_fill(const int* __restrict__ src, const int* __restrict__ dst,
                           int* __restrict__ cursor, int* __restrict__ csr_src) {
    int e = blockIdx.x * blockDim.x + threadIdx.x;
    if (e < N_EDGES) {
        int pos = atomicAdd(&cursor[dst[e]], 1);
        csr_src[pos] = src[e];
    }
}

// ---------------- aggregation (bf16 gather, f32 accum, no atomics) ----------------
__global__ __launch_bounds__(256) void k_agg_bf16(const unsigned short* __restrict__ in,
                                                  const float* __restrict__ dis,
                                                  const int* __restrict__ rowptr,
                                                  const int* __restrict__ csr_src,
                                                  unsigned short* __restrict__ out) {
    int node = blockIdx.x * 4 + (threadIdx.x >> 6);
    if (node >= N_NODES) return;
    int lane = threadIdx.x & 63;
    int f = lane * 4;

    float dn = dis[node];
    ushort4 sv = *(const ushort4*)(in + (size_t)node * DIM + f);
    float a0 = dn * bf2f(sv.x);
    float a1 = dn * bf2f(sv.y);
    float a2 = dn * bf2f(sv.z);
    float a3 = dn * bf2f(sv.w);

    int e = rowptr[node];
    int eEnd = rowptr[node + 1];
    for (; e + 3 < eEnd; e += 4) {
        int s0 = csr_src[e], s1 = csr_src[e + 1], s2 = csr_src[e + 2], s3 = csr_src[e + 3];
        float w0 = dis[s0], w1 = dis[s1], w2 = dis[s2], w3 = dis[s3];
        ushort4 v0 = *(const ushort4*)(in + (size_t)s0 * DIM + f);
        ushort4 v1 = *(const ushort4*)(in + (size_t)s1 * DIM + f);
        ushort4 v2 = *(const ushort4*)(in + (size_t)s2 * DIM + f);
        ushort4 v3 = *(const ushort4*)(in + (size_t)s3 * DIM + f);
        a0 += w0 * bf2f(v0.x) + w1 * bf2f(v1.x) + w2 * bf2f(v2.x) + w3 * bf2f(v3.x);
        a1 += w0 * bf2f(v0.y) + w1 * bf2f(v1.y) + w2 * bf2f(v2.y) + w3 * bf2f(v3.y);
        a2 += w0 * bf2f(v0.z) + w1 * bf2f(v1.z) + w2 * bf2f(v2.z) + w3 * bf2f(v3.z);
        a3 += w0 * bf2f(v0.w) + w1 * bf2f(v1.w) + w2 * bf2f(v2.w) + w3 * bf2f(v3.w);
    }
    for (; e < eEnd; ++e) {
        int s0 = csr_src[e];
        float w0 = dis[s0];
        ushort4 v0 = *(const ushort4*)(in + (size_t)s0 * DIM + f);
        a0 += w0 * bf2f(v0.x);
        a1 += w0 * bf2f(v0.y);
        a2 += w0 * bf2f(v0.z);
        a3 += w0 * bf2f(v0.w);
    }
    a0 *= dn; a1 *= dn; a2 *= dn; a3 *= dn;
    *(ushort4*)(out + (size_t)node * DIM + f) =
        make_ushort4(f2bf(a0), f2bf(a1), f2bf(a2), f2bf(a3));
}

// ---------------- wide MFMA GEMM: C = relu(A @ W + b), 128x256 tile (A read once) ----------------
__global__ __launch_bounds__(256) void k_gemm_wide(const unsigned short* __restrict__ A,
                                                   const unsigned short* __restrict__ Wt,
                                                   const float* __restrict__ bias,
                                                   unsigned short* __restrict__ C, int M) {
    __shared__ unsigned short As[4][128][8];   // 8 KB
    __shared__ unsigned short Bs[4][256][8];   // 16 KB

    int tid = threadIdx.x;
    int lane = tid & 63;
    int wave = tid >> 6;          // 32-row slice
    int lr = lane & 15;
    int lc = lane >> 4;

    int rowBase = blockIdx.x * 128;

    f32x4 acc[2][16] = {};

    int r = tid >> 2;             // 0..63
    int c = tid & 3;              // k-chunk

    for (int k0 = 0; k0 < DIM; k0 += 32) {
        float4 z = make_float4(0.f, 0.f, 0.f, 0.f);
        int gr0 = rowBase + r;
        int gr1 = rowBase + r + 64;
        float4 va0 = (gr0 < M) ? *(const float4*)(A + (size_t)gr0 * DIM + k0 + c * 8) : z;
        float4 va1 = (gr1 < M) ? *(const float4*)(A + (size_t)gr1 * DIM + k0 + c * 8) : z;
        *(float4*)&As[c][r][0]      = va0;
        *(float4*)&As[c][r + 64][0] = va1;
#pragma unroll
        for (int j = 0; j < 4; ++j) {
            int brow = r + 64 * j;
            *(float4*)&Bs[c][brow][0] = *(const float4*)(Wt + (size_t)brow * DIM + k0 + c * 8);
        }
        __syncthreads();

        bf16x8 af[2];
#pragma unroll
        for (int m = 0; m < 2; ++m)
            af[m] = *(const bf16x8*)&As[lc][wave * 32 + m * 16 + lr][0];
#pragma unroll
        for (int n = 0; n < 16; ++n) {
            bf16x8 bfr = *(const bf16x8*)&Bs[lc][n * 16 + lr][0];
            acc[0][n] = __builtin_amdgcn_mfma_f32_16x16x32_bf16(af[0], bfr, acc[0][n], 0, 0, 0);
            acc[1][n] = __builtin_amdgcn_mfma_f32_16x16x32_bf16(af[1], bfr, acc[1][n], 0, 0, 0);
        }
        __syncthreads();
    }

    float bv[16];
#pragma unroll
    for (int n = 0; n < 16; ++n) bv[n] = bias[n * 16 + lr];

#pragma unroll
    for (int m = 0; m < 2; ++m) {
#pragma unroll
        for (int reg = 0; reg < 4; ++reg) {
            int row = rowBase + wave * 32 + m * 16 + lc * 4 + reg;
            if (row < M) {
#pragma unroll
                for (int n = 0; n < 16; ++n) {
                    float v = fmaxf(acc[m][n][reg] + bv[n], 0.f);
                    C[(size_t)row * DIM + n * 16 + lr] = f2bf(v);
                }
            }
        }
    }
}

// ---------------- fused GEMM2 + FC + log_softmax ----------------
__global__ __launch_bounds__(256) void k_gemm_fc(const unsigned short* __restrict__ A,
                                                 const unsigned short* __restrict__ Wt,
                                                 const float* __restrict__ bias,
                                                 const float* __restrict__ Wfc,
                                                 const float* __restrict__ bfc,
                                                 float* __restrict__ out, int M) {
    __shared__ unsigned short As[4][128][8];   // 8 KB
    __shared__ unsigned short Bs[4][256][8];   // 16 KB

    int tid = threadIdx.x;
    int lane = tid & 63;
    int wave = tid >> 6;
    int lr = lane & 15;
    int lc = lane >> 4;

    int rowBase = blockIdx.x * 128;

    f32x4 acc[2][16] = {};

    int r = tid >> 2;
    int c = tid & 3;

    for (int k0 = 0; k0 < DIM; k0 += 32) {
        float4 z = make_float4(0.f, 0.f, 0.f, 0.f);
        int gr0 = rowBase + r;
        int gr1 = rowBase + r + 64;
        float4 va0 = (gr0 < M) ? *(const float4*)(A + (size_t)gr0 * DIM + k0 + c * 8) : z;
        float4 va1 = (gr1 < M) ? *(const float4*)(A + (size_t)gr1 * DIM + k0 + c * 8) : z;
        *(float4*)&As[c][r][0]      = va0;
        *(float4*)&As[c][r + 64][0] = va1;
#pragma unroll
        for (int j = 0; j < 4; ++j) {
            int brow = r + 64 * j;
            *(float4*)&Bs[c][brow][0] = *(const float4*)(Wt + (size_t)brow * DIM + k0 + c * 8);
        }
        __syncthreads();

        bf16x8 af[2];
#pragma unroll
        for (int m = 0; m < 2; ++m)
            af[m] = *(const bf16x8*)&As[lc][wave * 32 + m * 16 + lr][0];
#pragma unroll
        for (int n = 0; n < 16; ++n) {
            bf16x8 bfr = *(const bf16x8*)&Bs[lc][n * 16 + lr][0];
            acc[0][n] = __builtin_amdgcn_mfma_f32_16x16x32_bf16(af[0], bfr, acc[0][n], 0, 0, 0);
            acc[1][n] = __builtin_amdgcn_mfma_f32_16x16x32_bf16(af[1], bfr, acc[1][n], 0, 0, 0);
        }
        __syncthreads();
    }

    float bv[16], wf0[16], wf1[16];
#pragma unroll
    for (int n = 0; n < 16; ++n) {
        int col = n * 16 + lr;
        bv[n]  = bias[col];
        wf0[n] = Wfc[col * 2 + 0];
        wf1[n] = Wfc[col * 2 + 1];
    }
    float bb0 = bfc[0], bb1 = bfc[1];

#pragma unroll
    for (int m = 0; m < 2; ++m) {
#pragma unroll
        for (int reg = 0; reg < 4; ++reg) {
            int row = rowBase + wave * 32 + m * 16 + lc * 4 + reg;
            float s0 = 0.f, s1 = 0.f;
#pragma unroll
            for (int n = 0; n < 16; ++n) {
                float v = fmaxf(acc[m][n][reg] + bv[n], 0.f);   // bias + relu (h2 in f32)
                s0 += v * wf0[n];
                s1 += v * wf1[n];
            }
#pragma unroll
            for (int o = 1; o < 16; o <<= 1) {
                s0 += __shfl_xor(s0, o);
                s1 += __shfl_xor(s1, o);
            }
            if (lr == 0 && row < M) {
                float l0 = s0 + bb0;
                float l1 = s1 + bb1;
                float mx = fmaxf(l0, l1);
                float lse = mx + logf(expf(l0 - mx) + expf(l1 - mx));
                out[(size_t)row * 2 + 0] = l0 - lse;
                out[(size_t)row * 2 + 1] = l1 - lse;
            }
        }
    }
}

// ---------------- launch ----------------
extern "C" void kernel_launch(void* const* d_in, const int* in_sizes, int n_in,
                              void* d_out, int out_size, void* d_ws, size_t ws_size,
                              hipStream_t stream) {
    const float* x      = (const float*)d_in[0];
    const int* ei       = (const int*)d_in[1];   // int32 from harness
    const int* esrc     = ei;
    const int* edst     = ei + N_EDGES;
    const float* W1  = (const float*)d_in[2];
    const float* b1  = (const float*)d_in[3];
    const float* W2  = (const float*)d_in[4];
    const float* b2  = (const float*)d_in[5];
    const float* Wfc = (const float*)d_in[6];
    const float* bfc = (const float*)d_in[7];
    float* out = (float*)d_out;

    const size_t NF = (size_t)N_NODES * DIM;
    unsigned short* P0 = (unsigned short*)d_ws;          // xb, later a2b
    unsigned short* P1 = P0 + NF;                        // a1b
    unsigned short* P2 = P1 + NF;                        // h1b
    unsigned short* W1t = P2 + NF;                       // 256*256
    unsigned short* W2t = W1t + 256 * 256;
    float* dis    = (float*)(W2t + 256 * 256);           // N
    int* ideg     = (int*)(dis + N_NODES);               // N
    int* rowptr   = ideg + N_NODES;                      // N+1
    int* cursor   = rowptr + N_NODES + 1;                // N
    int* blocksum = cursor + N_NODES;                    // 256
    int* csr_src  = blocksum + 256;                      // E

    // CSR build + converts (ideg zeroed by async memset, then fused prep w/ deg_count)
    hipMemsetAsync(ideg, 0, N_NODES * sizeof(int), stream);
    k_prep<<<NXBLK + 512 + NDEGBLK, 256, 0, stream>>>(x, P0, W1, W1t, W2, W2t, edst, ideg);
    k_scan_block<<<SCAN_BLOCKS, 256, 0, stream>>>(ideg, rowptr, blocksum);
    k_scan_add<<<SCAN_BLOCKS, 256, 0, stream>>>(rowptr, blocksum, cursor, ideg, dis);
    k_csr_fill<<<(N_EDGES + 255) / 256, 256, 0, stream>>>(esrc, edst, cursor, csr_src);

    int aggBlocks = (N_NODES + 3) / 4;
    int gemmBlocks = (N_NODES + 127) / 128;

    // layer 1
    k_agg_bf16<<<aggBlocks, 256, 0, stream>>>(P0, dis, rowptr, csr_src, P1);
    k_gemm_wide<<<gemmBlocks, 256, 0, stream>>>(P1, W1t, b1, P2, N_NODES);

    // layer 2 + FC fused
    k_agg_bf16<<<aggBlocks, 256, 0, stream>>>(P2, dis, rowptr, csr_src, P0);
    k_gemm_fc<<<gemmBlocks, 256, 0, stream>>>(P0, W2t, b2, Wfc, bfc, out, N_NODES);
}